// Round 9
// baseline (322.839 us; speedup 1.0000x reference)
//
#include <hip/hip_runtime.h>
#include <hip/hip_bf16.h>

#define N_NODES 50000
#define C 128
#define NPAD 50176            // 3136 row-tiles of 16; 392 blocks * 8 tiles
#define NTILES (NPAD / 16)
#define GEMM_BLOCKS (NTILES / 8)  // 392
#define SCAN1_BLOCKS (NPAD / 256) // 196
#define XPREP_BLOCKS 3125         // 800000 / 256
#define WPREP_BLOCKS 256

typedef short bf16x8 __attribute__((ext_vector_type(8)));
typedef float f32x4 __attribute__((ext_vector_type(4)));

__device__ __forceinline__ unsigned short f2bf(float f) {
    unsigned int u = __float_as_uint(f);
    unsigned int r = u + 0x7fffu + ((u >> 16) & 1u);
    return (unsigned short)(r >> 16);
}

__device__ __forceinline__ float bf2f(unsigned short b) {
    return __uint_as_float(((unsigned int)b) << 16);
}

// ---- fused: degree histogram + x->bf16 cast + weight cast (block-range split)
__global__ __launch_bounds__(256) void build_kernel(
    const int* __restrict__ dst, int* __restrict__ deg, int E, int edgeBlocks,
    const float* __restrict__ x, unsigned short* __restrict__ Xb,
    const float* __restrict__ Wl1, const float* __restrict__ Wr1,
    const float* __restrict__ Wl2, const float* __restrict__ Wr2,
    unsigned short* __restrict__ Wc1, unsigned short* __restrict__ Wc2) {
    int b = blockIdx.x;
    if (b < edgeBlocks) {
        int e = b * 256 + threadIdx.x;
        if (e < E) {
            int d = dst[e];
            if ((unsigned)d < (unsigned)N_NODES) atomicAdd(deg + d, 1);
        }
    } else if (b < edgeBlocks + XPREP_BLOCKS) {
        int t = (b - edgeBlocks) * 256 + threadIdx.x;
        if (t >= N_NODES * C / 8) return;
        const float4 a = *(const float4*)(x + (size_t)t * 8);
        const float4 c = *(const float4*)(x + (size_t)t * 8 + 4);
        unsigned short o[8] = {f2bf(a.x), f2bf(a.y), f2bf(a.z), f2bf(a.w),
                               f2bf(c.x), f2bf(c.y), f2bf(c.z), f2bf(c.w)};
        *(uint4*)(Xb + (size_t)t * 8) = *(const uint4*)o;
    } else {
        int idx = (b - edgeBlocks - XPREP_BLOCKS) * 256 + threadIdx.x;  // 65536
        int layer = idx >> 15;
        int r = idx & 32767;
        int j = r >> 8, k = r & 255;
        const float* Wl = layer ? Wl2 : Wl1;
        const float* Wr = layer ? Wr2 : Wr1;
        unsigned short* Wc = layer ? Wc2 : Wc1;
        float f = (k < 128) ? Wl[j * 128 + k] : Wr[j * 128 + (k - 128)];
        Wc[r] = f2bf(f);
    }
}

// ---- hierarchical exclusive scan, phases 1-2 (phase 3 folded into consumers)
__global__ __launch_bounds__(256) void scan1_kernel(const int* __restrict__ deg,
                                                    int* __restrict__ scanbuf,
                                                    int* __restrict__ blocksum) {
    int i = blockIdx.x * 256 + threadIdx.x;
    int v = (i < N_NODES) ? deg[i] : 0;
    int lane = threadIdx.x & 63;
    int wv = threadIdx.x >> 6;
    int s = v;
#pragma unroll
    for (int off = 1; off < 64; off <<= 1) {
        int t = __shfl_up(s, off, 64);
        if (lane >= off) s += t;
    }
    __shared__ int wsum[4];
    if (lane == 63) wsum[wv] = s;
    __syncthreads();
    int woff = 0;
#pragma unroll
    for (int k = 0; k < 4; ++k) woff += (k < wv) ? wsum[k] : 0;
    scanbuf[i] = s + woff - v;                       // block-local exclusive
    if (threadIdx.x == 255) blocksum[blockIdx.x] = s + woff;  // block total
}

__global__ __launch_bounds__(256) void scan2_kernel(const int* __restrict__ blocksum,
                                                    int* __restrict__ blockoff) {
    int t = threadIdx.x;
    int v = (t < SCAN1_BLOCKS) ? blocksum[t] : 0;
    int lane = t & 63, wv = t >> 6;
    int s = v;
#pragma unroll
    for (int off = 1; off < 64; off <<= 1) {
        int tmp = __shfl_up(s, off, 64);
        if (lane >= off) s += tmp;
    }
    __shared__ int wsum[4];
    if (lane == 63) wsum[wv] = s;
    __syncthreads();
    int woff = 0;
#pragma unroll
    for (int k = 0; k < 4; ++k) woff += (k < wv) ? wsum[k] : 0;
    if (t < SCAN1_BLOCKS) blockoff[t] = s + woff - v;   // exclusive block offsets
}

// row_ptr(i) = scanbuf[i] + blockoff[i>>8], computed inline by consumers

// ---- fill CSR (row_ptr on the fly)
__global__ void fill_kernel(const int* __restrict__ src, const int* __restrict__ dst,
                            const int* __restrict__ scanbuf, const int* __restrict__ blockoff,
                            int* __restrict__ cursor, int* __restrict__ csr_src, int E) {
    int e = blockIdx.x * 256 + threadIdx.x;
    if (e < E) {
        int d = dst[e];
        int s = src[e];
        if ((unsigned)d < (unsigned)N_NODES && (unsigned)s < (unsigned)N_NODES) {
            int rp = scanbuf[d] + blockoff[d >> 8];
            int pos = rp + atomicAdd(cursor + d, 1);
            csr_src[pos] = s;
        }
    }
}

// ---- fused gather + GEMM layer:
// Each block owns 128 rows. Each wave pair-gathers its 32 rows' means into an
// LDS tile, then MFMAs: A-mean from LDS, A-self from global feat, B from global
// Wc (64 KB, L1/L2-resident). out[n][j] = [mean|self].Wc[j] + bias[j].
__global__ __launch_bounds__(256) void fused_layer(
    const unsigned short* __restrict__ feat,   // [NPAD,128] bf16 (Xb or h)
    const int* __restrict__ scanbuf, const int* __restrict__ blockoff,
    const int* __restrict__ csr_src,
    const unsigned short* __restrict__ Wc,     // [128,256] bf16
    const float* __restrict__ bias,            // [128]
    void* __restrict__ outv, int relu, int obf16) {
    __shared__ unsigned short smean[128 * 136];  // 34.8 KB, pitch 136 (bank shift 4)
    const int wave = threadIdx.x >> 6;
    const int lane = threadIdx.x & 63;
    const int tile0 = blockIdx.x * 8 + wave * 2;
    const int row0 = tile0 * 16;      // this wave's 32 global rows
    const int lrow0 = wave * 32;      // this wave's 32 LDS rows

    // -- gather phase: node pairs for MLP
    const unsigned short* fp = feat + lane * 2;
    for (int r = 0; r < 32; r += 2) {
        const int n0 = row0 + r;
        if (n0 >= N_NODES) {
            *(unsigned int*)(&smean[(lrow0 + r) * 136 + lane * 2]) = 0u;
            *(unsigned int*)(&smean[(lrow0 + r + 1) * 136 + lane * 2]) = 0u;
            continue;
        }
        const int beg0 = scanbuf[n0] + blockoff[n0 >> 8];
        const int mid  = scanbuf[n0 + 1] + blockoff[(n0 + 1) >> 8];
        const int end1 = scanbuf[n0 + 2] + blockoff[(n0 + 2) >> 8];
        float ax0 = 0.f, ay0 = 0.f, ax1 = 0.f, ay1 = 0.f;
        for (int base = beg0; base < end1; base += 64) {
            const int cnt = min(64, end1 - base);
            int myidx = (lane < cnt) ? csr_src[base + lane] : 0;
            int j = 0;
            for (; j + 7 < cnt; j += 8) {
                unsigned int u[8];
#pragma unroll
                for (int l = 0; l < 8; ++l) {
                    int s = __shfl(myidx, j + l);
                    u[l] = *(const unsigned int*)(fp + (size_t)s * C);
                }
#pragma unroll
                for (int l = 0; l < 8; ++l) {
                    float vx = bf2f((unsigned short)u[l]);
                    float vy = bf2f((unsigned short)(u[l] >> 16));
                    if (base + j + l < mid) { ax0 += vx; ay0 += vy; }
                    else                    { ax1 += vx; ay1 += vy; }
                }
            }
            for (; j < cnt; ++j) {
                int s = __shfl(myidx, j);
                unsigned int uu = *(const unsigned int*)(fp + (size_t)s * C);
                float vx = bf2f((unsigned short)uu);
                float vy = bf2f((unsigned short)(uu >> 16));
                if (base + j < mid) { ax0 += vx; ay0 += vy; }
                else                { ax1 += vx; ay1 += vy; }
            }
        }
        const float inv0 = 1.0f / fmaxf((float)(mid - beg0), 1.0f);
        const float inv1 = 1.0f / fmaxf((float)(end1 - mid), 1.0f);
        unsigned int p0 = (unsigned)f2bf(ax0 * inv0) | ((unsigned)f2bf(ay0 * inv0) << 16);
        unsigned int p1 = (unsigned)f2bf(ax1 * inv1) | ((unsigned)f2bf(ay1 * inv1) << 16);
        *(unsigned int*)(&smean[(lrow0 + r) * 136 + lane * 2]) = p0;
        *(unsigned int*)(&smean[(lrow0 + r + 1) * 136 + lane * 2]) = p1;
    }
    __syncthreads();   // waves only read their own tile; barrier is belt-and-braces

    // -- GEMM phase
    const int m = lane & 15;
    const int q = lane >> 4;
    const unsigned short* as = feat + (size_t)(row0 + m) * C + q * 8;   // self half
    const unsigned short* lm = &smean[(lrow0 + m) * 136 + q * 8];       // mean half (LDS)

    f32x4 acc[2][8];
#pragma unroll
    for (int t = 0; t < 2; ++t)
#pragma unroll
        for (int j = 0; j < 8; ++j) acc[t][j] = (f32x4){0.f, 0.f, 0.f, 0.f};

#pragma unroll
    for (int kt = 0; kt < 8; ++kt) {
        bf16x8 af0, af1;
        if (kt < 4) {
            af0 = *(const bf16x8*)(lm + kt * 32);
            af1 = *(const bf16x8*)(lm + 16 * 136 + kt * 32);
        } else {
            const int ko = (kt - 4) * 32;
            af0 = *(const bf16x8*)(as + ko);
            af1 = *(const bf16x8*)(as + 16 * C + ko);
        }
#pragma unroll
        for (int jt = 0; jt < 8; ++jt) {
            bf16x8 bfrag = *(const bf16x8*)(Wc + (jt * 16 + m) * 256 + kt * 32 + q * 8);
            acc[0][jt] = __builtin_amdgcn_mfma_f32_16x16x32_bf16(af0, bfrag, acc[0][jt], 0, 0, 0);
            acc[1][jt] = __builtin_amdgcn_mfma_f32_16x16x32_bf16(af1, bfrag, acc[1][jt], 0, 0, 0);
        }
    }

#pragma unroll
    for (int t = 0; t < 2; ++t) {
        int rbase = (tile0 + t) * 16 + q * 4;
#pragma unroll
        for (int r = 0; r < 4; ++r) {
            int row = rbase + r;
            if (row < N_NODES) {
#pragma unroll
                for (int jt = 0; jt < 8; ++jt) {
                    int col = jt * 16 + m;
                    float v = acc[t][jt][r] + bias[col];
                    if (relu) v = fmaxf(v, 0.0f);
                    if (obf16)
                        ((unsigned short*)outv)[(size_t)row * C + col] = f2bf(v);
                    else
                        ((float*)outv)[(size_t)row * C + col] = v;
                }
            }
        }
    }
}

extern "C" void kernel_launch(void* const* d_in, const int* in_sizes, int n_in,
                              void* d_out, int out_size, void* d_ws, size_t ws_size,
                              hipStream_t stream) {
    const float* x = (const float*)d_in[0];
    const int* edge = (const int*)d_in[1];   // int64 in reference -> int32 in harness
    const float* Wl1 = (const float*)d_in[2];
    const float* bl1 = (const float*)d_in[3];
    const float* Wr1 = (const float*)d_in[4];
    const float* Wl2 = (const float*)d_in[5];
    const float* bl2 = (const float*)d_in[6];
    const float* Wr2 = (const float*)d_in[7];
    float* out = (float*)d_out;

    const int E = in_sizes[1] / 2;
    const int* src = edge;
    const int* dst = edge + E;

    // workspace layout (deg and cursor contiguous -> one memset)
    char* ws = (char*)d_ws;
    size_t off = 0;
    int* deg = (int*)(ws + off);              off += (size_t)N_NODES * 4;
    int* cursor = (int*)(ws + off);           off += (size_t)N_NODES * 4;
    off = (off + 511) & ~511ull;
    int* scanbuf = (int*)(ws + off);          off += ((size_t)NPAD * 4 + 511) & ~511ull;
    int* blocksum = (int*)(ws + off);         off += 512 * 4;
    int* blockoff = (int*)(ws + off);         off += 512 * 4;
    int* csr_src = (int*)(ws + off);          off += ((size_t)E * 4 + 511) & ~511ull;
    unsigned short* Xb = (unsigned short*)(ws + off); off += (size_t)NPAD * C * 2;  // 12.8 MB
    unsigned short* h  = (unsigned short*)(ws + off); off += (size_t)NPAD * C * 2;  // 12.8 MB
    unsigned short* Wc1 = (unsigned short*)(ws + off); off += 128 * 256 * 2;
    unsigned short* Wc2 = (unsigned short*)(ws + off); off += 128 * 256 * 2;
    (void)ws_size;

    const int edgeBlocks = (E + 255) / 256;

    // CSR build + feature/weight conversion
    hipMemsetAsync(deg, 0, (size_t)N_NODES * 8, stream);  // deg + cursor
    build_kernel<<<edgeBlocks + XPREP_BLOCKS + WPREP_BLOCKS, 256, 0, stream>>>(
        dst, deg, E, edgeBlocks, x, Xb, Wl1, Wr1, Wl2, Wr2, Wc1, Wc2);
    scan1_kernel<<<SCAN1_BLOCKS, 256, 0, stream>>>(deg, scanbuf, blocksum);
    scan2_kernel<<<1, 256, 0, stream>>>(blocksum, blockoff);
    fill_kernel<<<edgeBlocks, 256, 0, stream>>>(src, dst, scanbuf, blockoff, cursor, csr_src, E);

    // layer 1: gather+gemm fused -> h (bf16, relu)
    fused_layer<<<GEMM_BLOCKS, 256, 0, stream>>>(Xb, scanbuf, blockoff, csr_src,
                                                 Wc1, bl1, h, 1, 1);
    // layer 2: gather+gemm fused -> out (fp32)
    fused_layer<<<GEMM_BLOCKS, 256, 0, stream>>>(h, scanbuf, blockoff, csr_src,
                                                 Wc2, bl2, out, 0, 0);
}